// Round 5
// baseline (5288.219 us; speedup 1.0000x reference)
//
#include <hip/hip_runtime.h>

// GCN layer: out = A_coo @ (X @ W) + b
// N=100000 nodes, E=3200000 edges, D_IN=D_OUT=256.
//
// R8: src-bucket phased aggregation (locality fix, not MLP fix).
// Evidence: R3/R5/R6 (three MLP structures, occ 45-66%) all plateau at
// 3.83-3.93 TB/s with FETCH=764MB vs ~130MB cached-ideal -> the random
// S-row gather is fetch-path-limited; only locality helps.
//  - edges sorted by key = (dst/64)*16 + bucket(src), bucket = src/6250
//    (3.2 MB of S per bucket, fits per-XCD L2).
//  - aggregate3: block owns 64 dst nodes, f32 acc in 64KB LDS, iterates
//    buckets IN ORDER -> all resident blocks touch the same 3.2MB S slice
//    at the same time (natural pacing; correctness timing-independent).
//  - per-edge: 4x LDS atomicAdd (ds_add_f32, fire-and-forget); node id
//    from 1-byte dloc sidecar -> no dependent boundary walk.
//  - sort machinery shrinks to 25008 counters: 2-level scan (existing
//    kernels), erank eliminated (scatter atomics on scanned offsets).

typedef __bf16 bf16;
typedef bf16 bf16x4 __attribute__((ext_vector_type(4)));
typedef bf16 bf16x8 __attribute__((ext_vector_type(8)));
typedef float f32x4 __attribute__((ext_vector_type(4)));
typedef int i32x2 __attribute__((ext_vector_type(2)));

#define D_DIM 256
#define NB 16         // src buckets
#define BNODES 64     // dst nodes per aggregation block

__device__ __forceinline__ int bucket_of(unsigned s, unsigned magic) {
    unsigned b = (unsigned)(((unsigned long long)s * magic) >> 32);
    return b > (NB - 1) ? (NB - 1) : (int)b;
}

// ---- 1) pack W[256][256] fp32 -> bf16 MFMA B-fragment layout ----
__global__ void pack_w(const float* __restrict__ W, bf16* __restrict__ Wf) {
    int lane = threadIdx.x;           // 64
    int blk  = blockIdx.x;            // 128 = 8 kt * 16 nt
    int kt = blk >> 4, nt = blk & 15;
    int t = lane & 15, q = lane >> 4;
    int krow = kt * 32 + q * 8;
    int col  = nt * 16 + t;
    bf16x8 v;
#pragma unroll
    for (int j = 0; j < 8; ++j)
        v[j] = (bf16)W[(size_t)(krow + j) * D_DIM + col];
    ((bf16x8*)Wf)[(size_t)blk * 64 + lane] = v;
}

// ---- 2) GEMM: support = X @ W (bf16 out). One wave = 16 rows x 256 cols ----
__global__ void gemm_xw(const float* __restrict__ X, const bf16* __restrict__ Wf,
                        bf16* __restrict__ S, int N) {
    int wid  = blockIdx.x * 4 + (threadIdx.x >> 6);
    int base = wid * 16;
    if (base >= N) return;
    int lane = threadIdx.x & 63;
    int t = lane & 15, q = lane >> 4;

    const float* xrow = X + (size_t)(base + t) * D_DIM + q * 8;
    const bf16x8* wf = (const bf16x8*)Wf;

    f32x4 acc[16];
#pragma unroll
    for (int i = 0; i < 16; ++i) acc[i] = (f32x4){0.f, 0.f, 0.f, 0.f};

#pragma unroll
    for (int kt = 0; kt < 8; ++kt) {
        f32x4 x0 = *(const f32x4*)(xrow + kt * 32);
        f32x4 x1 = *(const f32x4*)(xrow + kt * 32 + 4);
        bf16x8 a;
        a[0] = (bf16)x0[0]; a[1] = (bf16)x0[1]; a[2] = (bf16)x0[2]; a[3] = (bf16)x0[3];
        a[4] = (bf16)x1[0]; a[5] = (bf16)x1[1]; a[6] = (bf16)x1[2]; a[7] = (bf16)x1[3];
#pragma unroll
        for (int nt = 0; nt < 16; ++nt) {
            bf16x8 bfr = wf[(size_t)(kt * 16 + nt) * 64 + lane];
            acc[nt] = __builtin_amdgcn_mfma_f32_16x16x32_bf16(a, bfr, acc[nt], 0, 0, 0);
        }
    }

#pragma unroll
    for (int nt = 0; nt < 16; ++nt) {
#pragma unroll
        for (int r = 0; r < 4; ++r) {
            S[(size_t)(base + q * 4 + r) * D_DIM + nt * 16 + t] = (bf16)acc[nt][r];
        }
    }
}

// ---- 3a) histogram over 25008 (block,bucket) keys. 8 edges/thread ----
__global__ void hist3(const int* __restrict__ esrc, const int* __restrict__ edst,
                      int* __restrict__ cnt, int E, unsigned magic) {
    int gid  = blockIdx.x * blockDim.x + threadIdx.x;
    int base = gid * 8;
    if (base + 8 <= E) {
        int4 s0 = *(const int4*)(esrc + base);
        int4 s1 = *(const int4*)(esrc + base + 4);
        int4 d0 = *(const int4*)(edst + base);
        int4 d1 = *(const int4*)(edst + base + 4);
        atomicAdd(&cnt[(d0.x >> 6) * NB + bucket_of(s0.x, magic)], 1);
        atomicAdd(&cnt[(d0.y >> 6) * NB + bucket_of(s0.y, magic)], 1);
        atomicAdd(&cnt[(d0.z >> 6) * NB + bucket_of(s0.z, magic)], 1);
        atomicAdd(&cnt[(d0.w >> 6) * NB + bucket_of(s0.w, magic)], 1);
        atomicAdd(&cnt[(d1.x >> 6) * NB + bucket_of(s1.x, magic)], 1);
        atomicAdd(&cnt[(d1.y >> 6) * NB + bucket_of(s1.y, magic)], 1);
        atomicAdd(&cnt[(d1.z >> 6) * NB + bucket_of(s1.z, magic)], 1);
        atomicAdd(&cnt[(d1.w >> 6) * NB + bucket_of(s1.w, magic)], 1);
    } else {
        for (int e = base; e < E; ++e)
            atomicAdd(&cnt[(edst[e] >> 6) * NB + bucket_of(esrc[e], magic)], 1);
    }
}

// ---- 3b) per-block exclusive scan (1024 elems/block) ----
__global__ void scan_block(const int* __restrict__ counts, int n,
                           int* __restrict__ local_ex, int* __restrict__ bsums) {
    __shared__ int lds[1024];
    int tid = threadIdx.x;
    int g = blockIdx.x * 1024 + tid;
    int v = (g < n) ? counts[g] : 0;
    lds[tid] = v;
    __syncthreads();
    for (int d = 1; d < 1024; d <<= 1) {
        int add = (tid >= d) ? lds[tid - d] : 0;
        __syncthreads();
        lds[tid] += add;
        __syncthreads();
    }
    if (g < n) local_ex[g] = lds[tid] - v;
    if (tid == 1023) bsums[blockIdx.x] = lds[tid];
}

// ---- 3c) scan of block sums (single block, nb <= 128) ----
__global__ void scan_sums(const int* __restrict__ bsums, int nb, int* __restrict__ bex) {
    __shared__ int lds[128];
    int tid = threadIdx.x;
    int v = (tid < nb) ? bsums[tid] : 0;
    lds[tid] = v;
    __syncthreads();
    for (int d = 1; d < 128; d <<= 1) {
        int add = (tid >= d) ? lds[tid - d] : 0;
        __syncthreads();
        lds[tid] += add;
        __syncthreads();
    }
    if (tid < nb) bex[tid] = lds[tid] - v;
}

// ---- 3d) add block base; dual-write (off3 for aggregate, cnt mutable for
//          scatter); sentinel off3[n] = E ----
__global__ void finalize_off(int* __restrict__ off, int* __restrict__ cntm,
                             const int* __restrict__ bex, int n, int E) {
    int g = blockIdx.x * 1024 + threadIdx.x;
    if (g < n) {
        int v = off[g] + bex[blockIdx.x];
        off[g]  = v;
        cntm[g] = v;
    }
    if (g == 0) off[n] = E;
}

// ---- 3e) scatter edges: pos = atomic bump of scanned offset ----
__global__ void scatter3(const int* __restrict__ esrc, const int* __restrict__ edst,
                         const float* __restrict__ evals, int* __restrict__ cntm,
                         i32x2* __restrict__ eP, unsigned char* __restrict__ dloc,
                         int E, unsigned magic) {
    int gid  = blockIdx.x * blockDim.x + threadIdx.x;
    int base = gid * 8;
    if (base + 8 <= E) {
        int4 s0 = *(const int4*)(esrc + base);
        int4 s1 = *(const int4*)(esrc + base + 4);
        int4 d0 = *(const int4*)(edst + base);
        int4 d1 = *(const int4*)(edst + base + 4);
        float4 v0 = *(const float4*)(evals + base);
        float4 v1 = *(const float4*)(evals + base + 4);
        int ss[8] = {s0.x, s0.y, s0.z, s0.w, s1.x, s1.y, s1.z, s1.w};
        int dd[8] = {d0.x, d0.y, d0.z, d0.w, d1.x, d1.y, d1.z, d1.w};
        float vv[8] = {v0.x, v0.y, v0.z, v0.w, v1.x, v1.y, v1.z, v1.w};
#pragma unroll
        for (int j = 0; j < 8; ++j) {
            int key = (dd[j] >> 6) * NB + bucket_of(ss[j], magic);
            int pos = atomicAdd(&cntm[key], 1);
            eP[pos] = (i32x2){ss[j], __float_as_int(vv[j])};
            dloc[pos] = (unsigned char)(dd[j] & 63);
        }
    } else {
        for (int e = base; e < E; ++e) {
            int key = (edst[e] >> 6) * NB + bucket_of(esrc[e], magic);
            int pos = atomicAdd(&cntm[key], 1);
            eP[pos] = (i32x2){esrc[e], __float_as_int(evals[e])};
            dloc[pos] = (unsigned char)(edst[e] & 63);
        }
    }
}

// ---- 4) aggregate3: block owns 64 dst nodes (f32 acc in LDS); iterates
//         src buckets in order so all resident blocks share a 3.2MB hot
//         S slice (L2/L3-resident). Per edge: 4x LDS atomicAdd.
__global__ void __launch_bounds__(256) aggregate3(
        const bf16* __restrict__ S, const int* __restrict__ off3,
        const i32x2* __restrict__ eP, const unsigned char* __restrict__ dloc,
        const float* __restrict__ b, float* __restrict__ out, int N) {
    __shared__ float accs[BNODES * D_DIM];     // 64 KB
    int tid  = threadIdx.x;
    int wid  = tid >> 6;
    int lane = tid & 63;
    int blk  = blockIdx.x;

    // init acc rows with bias
    const f32x4* b4 = (const f32x4*)b;
    f32x4* a4 = (f32x4*)accs;
#pragma unroll
    for (int i = 0; i < 16; ++i) {
        int idx = tid + i * 256;               // 0..4095
        a4[idx] = b4[idx & 63];
    }
    __syncthreads();

    for (int k = 0; k < NB; ++k) {
        int s = off3[blk * NB + k];
        int t = off3[blk * NB + k + 1];
        int cnt = t - s;
        int ws = s + ((cnt * wid) >> 2);
        int we = s + ((cnt * (wid + 1)) >> 2);
        int e = ws;
        for (; e + 8 <= we; e += 8) {
            i32x2 rr[8];
#pragma unroll
            for (int j = 0; j < 8; ++j) rr[j] = __builtin_nontemporal_load(&eP[e + j]);
            bf16x4 vv[8];
#pragma unroll
            for (int j = 0; j < 8; ++j)
                vv[j] = *((const bf16x4*)(S + (size_t)rr[j][0] * D_DIM) + lane);
            int lc[8];
#pragma unroll
            for (int j = 0; j < 8; ++j) lc[j] = (int)dloc[e + j];
#pragma unroll
            for (int j = 0; j < 8; ++j) {
                float wt = __int_as_float(rr[j][1]);
                float* row = &accs[lc[j] * D_DIM + lane * 4];
                atomicAdd(&row[0], wt * (float)vv[j][0]);
                atomicAdd(&row[1], wt * (float)vv[j][1]);
                atomicAdd(&row[2], wt * (float)vv[j][2]);
                atomicAdd(&row[3], wt * (float)vv[j][3]);
            }
        }
        for (; e < we; ++e) {
            i32x2 r = eP[e];
            bf16x4 v = *((const bf16x4*)(S + (size_t)r[0] * D_DIM) + lane);
            float wt = __int_as_float(r[1]);
            float* row = &accs[(int)dloc[e] * D_DIM + lane * 4];
            atomicAdd(&row[0], wt * (float)v[0]);
            atomicAdd(&row[1], wt * (float)v[1]);
            atomicAdd(&row[2], wt * (float)v[2]);
            atomicAdd(&row[3], wt * (float)v[3]);
        }
        __syncthreads();   // keep block's waves in phase (alignment heuristic)
    }

    // write out
#pragma unroll
    for (int i = 0; i < 16; ++i) {
        int idx  = tid + i * 256;
        int node = blk * BNODES + (idx >> 6);
        if (node < N)
            __builtin_nontemporal_store(a4[idx], (f32x4*)out + (size_t)node * 64 + (idx & 63));
    }
}

extern "C" void kernel_launch(void* const* d_in, const int* in_sizes, int n_in,
                              void* d_out, int out_size, void* d_ws, size_t ws_size,
                              hipStream_t stream) {
    const float* X     = (const float*)d_in[0];
    const int*   esrc  = (const int*)d_in[1];
    const int*   edst  = (const int*)d_in[2];
    const float* evals = (const float*)d_in[3];
    const float* W     = (const float*)d_in[4];
    const float* bias  = (const float*)d_in[5];
    float* out = (float*)d_out;

    const int N = in_sizes[0] / D_DIM;     // 100000
    const int E = in_sizes[1];             // 3200000

    const int NBLK3 = (N + BNODES - 1) / BNODES;   // 1563
    const int M2    = NBLK3 * NB;                  // 25008 keys
    // bucket(src) = umulhi(src, magic): ~N/NB nodes per bucket
    const unsigned magic = (unsigned)((((unsigned long long)NB << 32) + N - 1) / N);

    // workspace carve-up (256B aligned)
    auto alignup = [](size_t x) { return (x + 255) & ~(size_t)255; };
    char* ws = (char*)d_ws;
    size_t o = 0;
    bf16* S      = (bf16*)(ws + o); o = alignup(o + (size_t)N * D_DIM * sizeof(bf16));
    int* cnt3    = (int*)(ws + o);  o = alignup(o + (size_t)(M2 + 16) * sizeof(int));
    int* off3    = (int*)(ws + o);  o = alignup(o + (size_t)(M2 + 16) * sizeof(int));
    int* bsums   = (int*)(ws + o);  o = alignup(o + 1024 * sizeof(int));
    int* bex     = (int*)(ws + o);  o = alignup(o + 1024 * sizeof(int));
    i32x2* eP    = (i32x2*)(ws + o); o = alignup(o + (size_t)E * sizeof(i32x2));
    unsigned char* dloc = (unsigned char*)(ws + o); o = alignup(o + (size_t)E);
    bf16* Wf     = (bf16*)(ws + o); o = alignup(o + (size_t)D_DIM * D_DIM * sizeof(bf16));

    const int nwaves = (N + 15) / 16;              // gemm waves
    const int nb8    = ((E + 7) / 8 + 255) / 256;  // blocks for 8-edge kernels
    const int nbs    = (M2 + 1023) / 1024;         // 25 scan blocks (<=128)

    hipMemsetAsync(cnt3, 0, (size_t)(M2 + 16) * sizeof(int), stream);
    pack_w<<<128, 64, 0, stream>>>(W, Wf);
    gemm_xw<<<(nwaves + 3) / 4, 256, 0, stream>>>(X, Wf, S, N);
    hist3<<<nb8, 256, 0, stream>>>(esrc, edst, cnt3, E, magic);
    scan_block<<<nbs, 1024, 0, stream>>>(cnt3, M2, off3, bsums);
    scan_sums<<<1, 128, 0, stream>>>(bsums, nbs, bex);
    finalize_off<<<nbs, 1024, 0, stream>>>(off3, cnt3, bex, M2, E);
    scatter3<<<nb8, 256, 0, stream>>>(esrc, edst, evals, cnt3, eP, dloc, E, magic);
    aggregate3<<<NBLK3, 256, 0, stream>>>(S, off3, eP, dloc, bias, out, N);
}

// Round 6
// 736.681 us; speedup vs baseline: 7.1784x; 7.1784x over previous
//
#include <hip/hip_runtime.h>

// GCN layer: out = A_coo @ (X @ W) + b
// N=100000 nodes, E=3200000 edges, D_IN=D_OUT=256.
//
// R9 = R5 proven pipeline (664us total, aggregate 231us) + ONE change:
//   sort_node_edges: per-node in-place bitonic sort of eP segment by src.
//   All concurrent aggregate waves then walk src ids in ascending order ->
//   sliding ~10-15MB S window fits effective aggregate L2 (~24MB: 8 XCD x
//   4MB with random overlap; measured 53% miss matched 1-24/51 exactly).
// R8 lesson (5288us): LDS fp atomics are ~60-100cyc/wave64 op (VALU 1.7%)
//   -> register accumulation only; locality must come from edge ORDER.

typedef __bf16 bf16;
typedef bf16 bf16x4 __attribute__((ext_vector_type(4)));
typedef bf16 bf16x8 __attribute__((ext_vector_type(8)));
typedef float f32x4 __attribute__((ext_vector_type(4)));
typedef int i32x2 __attribute__((ext_vector_type(2)));

#define D_DIM 256

// ---- 1) pack W[256][256] fp32 -> bf16 MFMA B-fragment layout ----
__global__ void pack_w(const float* __restrict__ W, bf16* __restrict__ Wf) {
    int lane = threadIdx.x;           // 64
    int blk  = blockIdx.x;            // 128 = 8 kt * 16 nt
    int kt = blk >> 4, nt = blk & 15;
    int t = lane & 15, q = lane >> 4;
    int krow = kt * 32 + q * 8;
    int col  = nt * 16 + t;
    bf16x8 v;
#pragma unroll
    for (int j = 0; j < 8; ++j)
        v[j] = (bf16)W[(size_t)(krow + j) * D_DIM + col];
    ((bf16x8*)Wf)[(size_t)blk * 64 + lane] = v;
}

// ---- 2) GEMM: support = X @ W (bf16 out). One wave = 16 rows x 256 cols ----
__global__ void gemm_xw(const float* __restrict__ X, const bf16* __restrict__ Wf,
                        bf16* __restrict__ S, int N) {
    int wid  = blockIdx.x * 4 + (threadIdx.x >> 6);
    int base = wid * 16;
    if (base >= N) return;
    int lane = threadIdx.x & 63;
    int t = lane & 15, q = lane >> 4;

    const float* xrow = X + (size_t)(base + t) * D_DIM + q * 8;
    const bf16x8* wf = (const bf16x8*)Wf;

    f32x4 acc[16];
#pragma unroll
    for (int i = 0; i < 16; ++i) acc[i] = (f32x4){0.f, 0.f, 0.f, 0.f};

#pragma unroll
    for (int kt = 0; kt < 8; ++kt) {
        f32x4 x0 = *(const f32x4*)(xrow + kt * 32);
        f32x4 x1 = *(const f32x4*)(xrow + kt * 32 + 4);
        bf16x8 a;
        a[0] = (bf16)x0[0]; a[1] = (bf16)x0[1]; a[2] = (bf16)x0[2]; a[3] = (bf16)x0[3];
        a[4] = (bf16)x1[0]; a[5] = (bf16)x1[1]; a[6] = (bf16)x1[2]; a[7] = (bf16)x1[3];
#pragma unroll
        for (int nt = 0; nt < 16; ++nt) {
            bf16x8 bfr = wf[(size_t)(kt * 16 + nt) * 64 + lane];
            acc[nt] = __builtin_amdgcn_mfma_f32_16x16x32_bf16(a, bfr, acc[nt], 0, 0, 0);
        }
    }

#pragma unroll
    for (int nt = 0; nt < 16; ++nt) {
#pragma unroll
        for (int r = 0; r < 4; ++r) {
            S[(size_t)(base + q * 4 + r) * D_DIM + nt * 16 + t] = (bf16)acc[nt][r];
        }
    }
}

// ---- 3a) histogram + rank: rank[e] = old count of dst. 8 edges/thread ----
__global__ void rank_edges(const int* __restrict__ edst, int* __restrict__ counts,
                           int* __restrict__ erank, int E) {
    int gid  = blockIdx.x * blockDim.x + threadIdx.x;
    int base = gid * 8;
    if (base + 8 <= E) {
        int4 d0 = *(const int4*)(edst + base);
        int4 d1 = *(const int4*)(edst + base + 4);
        int4 r0, r1;
        r0.x = atomicAdd(&counts[d0.x], 1);
        r0.y = atomicAdd(&counts[d0.y], 1);
        r0.z = atomicAdd(&counts[d0.z], 1);
        r0.w = atomicAdd(&counts[d0.w], 1);
        r1.x = atomicAdd(&counts[d1.x], 1);
        r1.y = atomicAdd(&counts[d1.y], 1);
        r1.z = atomicAdd(&counts[d1.z], 1);
        r1.w = atomicAdd(&counts[d1.w], 1);
        *(int4*)(erank + base)     = r0;
        *(int4*)(erank + base + 4) = r1;
    } else {
        for (int e = base; e < E; ++e)
            erank[e] = atomicAdd(&counts[edst[e]], 1);
    }
}

// ---- 3b) per-block exclusive scan (1024 elems/block) ----
__global__ void scan_block(const int* __restrict__ counts, int n,
                           int* __restrict__ local_ex, int* __restrict__ bsums) {
    __shared__ int lds[1024];
    int tid = threadIdx.x;
    int g = blockIdx.x * 1024 + tid;
    int v = (g < n) ? counts[g] : 0;
    lds[tid] = v;
    __syncthreads();
    for (int d = 1; d < 1024; d <<= 1) {
        int add = (tid >= d) ? lds[tid - d] : 0;
        __syncthreads();
        lds[tid] += add;
        __syncthreads();
    }
    if (g < n) local_ex[g] = lds[tid] - v;
    if (tid == 1023) bsums[blockIdx.x] = lds[tid];
}

// ---- 3c) scan of block sums (single block, nb <= 128) ----
__global__ void scan_sums(const int* __restrict__ bsums, int nb, int* __restrict__ bex) {
    __shared__ int lds[128];
    int tid = threadIdx.x;
    int v = (tid < nb) ? bsums[tid] : 0;
    lds[tid] = v;
    __syncthreads();
    for (int d = 1; d < 128; d <<= 1) {
        int add = (tid >= d) ? lds[tid - d] : 0;
        __syncthreads();
        lds[tid] += add;
        __syncthreads();
    }
    if (tid < nb) bex[tid] = lds[tid] - v;
}

// ---- 3d) add block base; also writes sentinel off[n] = E ----
__global__ void add_base(int* __restrict__ off, const int* __restrict__ bex,
                         int n, int E) {
    int g = blockIdx.x * 1024 + threadIdx.x;
    if (g < n) off[g] += bex[blockIdx.x];
    if (g == 0) off[n] = E;
}

// ---- 3e) scatter edges (ATOMIC-FREE): pos = off[dst] + rank. 8/thread ----
__global__ void scatter_edges(const int* __restrict__ esrc, const int* __restrict__ edst,
                              const float* __restrict__ evals, const int* __restrict__ erank,
                              const int* __restrict__ off, i32x2* __restrict__ eP, int E) {
    int gid  = blockIdx.x * blockDim.x + threadIdx.x;
    int base = gid * 8;
    if (base + 8 <= E) {
        int4 s0 = *(const int4*)(esrc + base);
        int4 s1 = *(const int4*)(esrc + base + 4);
        int4 d0 = *(const int4*)(edst + base);
        int4 d1 = *(const int4*)(edst + base + 4);
        int4 r0 = *(const int4*)(erank + base);
        int4 r1 = *(const int4*)(erank + base + 4);
        float4 v0 = *(const float4*)(evals + base);
        float4 v1 = *(const float4*)(evals + base + 4);
        int p0 = off[d0.x] + r0.x;
        int p1 = off[d0.y] + r0.y;
        int p2 = off[d0.z] + r0.z;
        int p3 = off[d0.w] + r0.w;
        int p4 = off[d1.x] + r1.x;
        int p5 = off[d1.y] + r1.y;
        int p6 = off[d1.z] + r1.z;
        int p7 = off[d1.w] + r1.w;
        eP[p0] = (i32x2){s0.x, __float_as_int(v0.x)};
        eP[p1] = (i32x2){s0.y, __float_as_int(v0.y)};
        eP[p2] = (i32x2){s0.z, __float_as_int(v0.z)};
        eP[p3] = (i32x2){s0.w, __float_as_int(v0.w)};
        eP[p4] = (i32x2){s1.x, __float_as_int(v1.x)};
        eP[p5] = (i32x2){s1.y, __float_as_int(v1.y)};
        eP[p6] = (i32x2){s1.z, __float_as_int(v1.z)};
        eP[p7] = (i32x2){s1.w, __float_as_int(v1.w)};
    } else {
        for (int e = base; e < E; ++e) {
            eP[off[edst[e]] + erank[e]] = (i32x2){esrc[e], __float_as_int(evals[e])};
        }
    }
}

// ---- 3f) per-node in-place sort of eP segment by src (64-chunk bitonic).
// Perf heuristic only: ascending-src edge order => all concurrent aggregate
// waves share a sliding S window (~10-15MB) that fits aggregate L2.
__global__ void __launch_bounds__(256) sort_node_edges(
        const int* __restrict__ off, i32x2* __restrict__ eP, int N) {
    int w = blockIdx.x * 4 + (threadIdx.x >> 6);
    if (w >= N) return;
    int lane = threadIdx.x & 63;
    int s = off[w], e = off[w + 1];
    for (int base = s; base < e; base += 64) {
        int m = e - base; if (m > 64) m = 64;
        int key = 0x7fffffff, pay = 0;
        if (lane < m) { i32x2 p = eP[base + lane]; key = p[0]; pay = p[1]; }
#pragma unroll
        for (int k = 2; k <= 64; k <<= 1) {
#pragma unroll
            for (int j = k >> 1; j > 0; j >>= 1) {
                int ok = __shfl_xor(key, j);
                int op = __shfl_xor(pay, j);
                bool lower = (lane & j) == 0;
                bool up    = (lane & k) == 0;
                bool take  = up ? (lower ? (ok < key) : (ok > key))
                                : (lower ? (ok > key) : (ok < key));
                if (take) { key = ok; pay = op; }
            }
        }
        if (lane < m) eP[base + lane] = (i32x2){key, pay};
    }
}

// ---- 4) aggregate: one wave per node; lane owns cols [lane*4, lane*4+4) ----
// (proven R5 version, 230.8us at unsorted order)
__global__ void __launch_bounds__(256) aggregate(
        const bf16* __restrict__ S, const int* __restrict__ off,
        const i32x2* __restrict__ eP, const float* __restrict__ b,
        float* __restrict__ out, int N) {
    int w = blockIdx.x * 4 + (threadIdx.x >> 6);
    if (w >= N) return;
    int lane = threadIdx.x & 63;

    f32x4 acc = ((const f32x4*)b)[lane];

    int e   = off[w];
    int end = off[w + 1];

    // main: 16 edges in flight
    for (; e + 16 <= end; e += 16) {
        i32x2 r[16];
#pragma unroll
        for (int j = 0; j < 16; ++j) r[j] = __builtin_nontemporal_load(&eP[e + j]);
        bf16x4 v[16];
#pragma unroll
        for (int j = 0; j < 16; ++j)
            v[j] = *((const bf16x4*)(S + (size_t)r[j][0] * D_DIM) + lane);
#pragma unroll
        for (int j = 0; j < 16; ++j) {
            float wt = __int_as_float(r[j][1]);
            acc[0] += wt * (float)v[j][0];
            acc[1] += wt * (float)v[j][1];
            acc[2] += wt * (float)v[j][2];
            acc[3] += wt * (float)v[j][3];
        }
    }
    // mid: 4 at a time
    for (; e + 4 <= end; e += 4) {
        i32x2 r[4];
#pragma unroll
        for (int j = 0; j < 4; ++j) r[j] = __builtin_nontemporal_load(&eP[e + j]);
        bf16x4 v[4];
#pragma unroll
        for (int j = 0; j < 4; ++j)
            v[j] = *((const bf16x4*)(S + (size_t)r[j][0] * D_DIM) + lane);
#pragma unroll
        for (int j = 0; j < 4; ++j) {
            float wt = __int_as_float(r[j][1]);
            acc[0] += wt * (float)v[j][0];
            acc[1] += wt * (float)v[j][1];
            acc[2] += wt * (float)v[j][2];
            acc[3] += wt * (float)v[j][3];
        }
    }
    for (; e < end; ++e) {
        i32x2 r = eP[e];
        float wt = __int_as_float(r[1]);
        bf16x4 v = *((const bf16x4*)(S + (size_t)r[0] * D_DIM) + lane);
        acc[0] += wt * (float)v[0];
        acc[1] += wt * (float)v[1];
        acc[2] += wt * (float)v[2];
        acc[3] += wt * (float)v[3];
    }
    __builtin_nontemporal_store(acc, (f32x4*)out + (size_t)w * 64 + lane);
}

extern "C" void kernel_launch(void* const* d_in, const int* in_sizes, int n_in,
                              void* d_out, int out_size, void* d_ws, size_t ws_size,
                              hipStream_t stream) {
    const float* X     = (const float*)d_in[0];
    const int*   esrc  = (const int*)d_in[1];
    const int*   edst  = (const int*)d_in[2];
    const float* evals = (const float*)d_in[3];
    const float* W     = (const float*)d_in[4];
    const float* bias  = (const float*)d_in[5];
    float* out = (float*)d_out;

    const int N = in_sizes[0] / D_DIM;   // 100000
    const int E = in_sizes[1];           // 3200000

    // workspace carve-up (256B aligned)
    auto alignup = [](size_t x) { return (x + 255) & ~(size_t)255; };
    char* ws = (char*)d_ws;
    size_t o = 0;
    bf16* S      = (bf16*)(ws + o); o = alignup(o + (size_t)N * D_DIM * sizeof(bf16));
    int* counts  = (int*)(ws + o);  o = alignup(o + (size_t)N * sizeof(int));
    int* off     = (int*)(ws + o);  o = alignup(o + (size_t)(N + 1) * sizeof(int));
    int* erank   = (int*)(ws + o);  o = alignup(o + (size_t)E * sizeof(int));
    int* bsums   = (int*)(ws + o);  o = alignup(o + 1024 * sizeof(int));
    int* bex     = (int*)(ws + o);  o = alignup(o + 1024 * sizeof(int));
    i32x2* eP    = (i32x2*)(ws + o); o = alignup(o + (size_t)E * sizeof(i32x2));
    bf16* Wf     = (bf16*)(ws + o); o = alignup(o + (size_t)D_DIM * D_DIM * sizeof(bf16));

    const int nb = (N + 1023) / 1024;        // 98 (<=128 required by scan_sums)
    const int nwaves = (N + 15) / 16;        // 6250
    const int nthr8 = (E + 7) / 8;           // threads for 8-edge kernels

    hipMemsetAsync(counts, 0, (size_t)N * sizeof(int), stream);
    pack_w<<<128, 64, 0, stream>>>(W, Wf);
    gemm_xw<<<(nwaves + 3) / 4, 256, 0, stream>>>(X, Wf, S, N);
    rank_edges<<<(nthr8 + 255) / 256, 256, 0, stream>>>(edst, counts, erank, E);
    scan_block<<<nb, 1024, 0, stream>>>(counts, N, off, bsums);
    scan_sums<<<1, 128, 0, stream>>>(bsums, nb, bex);
    add_base<<<nb, 1024, 0, stream>>>(off, bex, N, E);
    scatter_edges<<<(nthr8 + 255) / 256, 256, 0, stream>>>(esrc, edst, evals, erank, off, eP, E);
    sort_node_edges<<<(N + 3) / 4, 256, 0, stream>>>(off, eP, N);
    aggregate<<<(N + 3) / 4, 256, 0, stream>>>(S, off, eP, bias, out, N);
}